// Round 2
// baseline (610.561 us; speedup 1.0000x reference)
//
#include <hip/hip_runtime.h>
#include <math.h>

// Problem constants
#define KCL   8192      // clusters
#define DIM   64        // embedding dim
#define NPTS  32768     // B*H*W
#define HW    1024      // H*W
#define PLANE 65536     // D*H*W (per-batch stride in z)

// -------------------- e2[k] = ||embedding[k]||^2 --------------------
__global__ __launch_bounds__(256) void e2_kernel(const float* __restrict__ emb,
                                                 float* __restrict__ e2) {
    int k = blockIdx.x * 256 + threadIdx.x;
    const float4* row = (const float4*)(emb + (size_t)k * DIM);
    float s = 0.f;
#pragma unroll
    for (int i = 0; i < DIM / 4; ++i) {
        float4 v = row[i];
        s += v.x * v.x + v.y * v.y + v.z * v.z + v.w * v.w;
    }
    e2[k] = s;
}

// -------------------- main fused kernel --------------------
// Each block: 64 consecutive points (same b), full K loop in chunks of 64.
// Thread (pg,cg) = (t/16, t%16) computes a 4x4 (points x clusters) register tile.
__global__ __launch_bounds__(256) void vq_main(
    const float* __restrict__ z, const float* __restrict__ emb,
    const float* __restrict__ e2g, float* __restrict__ counts,
    float* __restrict__ bavg, float* __restrict__ loss_ws,
    float* __restrict__ zq_out, float* __restrict__ idx_out) {
    __shared__ float z_lds[64 * 68];
    __shared__ float e_lds[64 * 68];
    __shared__ float e2_lds[64];

    const int t   = threadIdx.x;
    const int pg  = t >> 4;   // 0..15 point group
    const int cg  = t & 15;   // 0..15 cluster group
    const int p0  = blockIdx.x * 64;  // global point base
    const int b   = p0 >> 10;
    const int hw0 = p0 & 1023;
    const float* zb = z + (size_t)b * PLANE + hw0;

    // load z tile into LDS as [d][p] (stride 68): 64 d-rows x 64 points.
    // 1024 float4s total -> 4 per thread. 16 lanes cover one 256B row segment.
    {
        int seg = t & 15, d0 = t >> 4;
#pragma unroll
        for (int r = 0; r < 4; ++r) {
            int d = d0 + 16 * r;
            float4 v = *(const float4*)(zb + d * HW + 4 * seg);
            *(float4*)&z_lds[d * 68 + 4 * seg] = v;
        }
    }

    float best[4];
    int   bestk[4];
#pragma unroll
    for (int i = 0; i < 4; ++i) { best[i] = 3.4e38f; bestk[i] = 0; }

    for (int k0 = 0; k0 < KCL; k0 += 64) {
        __syncthreads();
        {   // load e chunk transposed into [d][c] (stride 68): 64 clusters x 64 dims
            int c = t >> 2, s0 = t & 3;
#pragma unroll
            for (int r = 0; r < 4; ++r) {
                int seg = s0 + 4 * r;   // float4 index within the cluster row
                float4 v = *(const float4*)(emb + (size_t)(k0 + c) * DIM + 4 * seg);
                e_lds[(4 * seg + 0) * 68 + c] = v.x;
                e_lds[(4 * seg + 1) * 68 + c] = v.y;
                e_lds[(4 * seg + 2) * 68 + c] = v.z;
                e_lds[(4 * seg + 3) * 68 + c] = v.w;
            }
            if (t < 64) e2_lds[t] = e2g[k0 + t];
        }
        __syncthreads();

        float acc[4][4];
#pragma unroll
        for (int i = 0; i < 4; ++i)
#pragma unroll
            for (int j = 0; j < 4; ++j) acc[i][j] = 0.f;

#pragma unroll 4
        for (int d = 0; d < 64; ++d) {
            float4 zv = *(const float4*)&z_lds[d * 68 + 4 * pg];
            float4 ev = *(const float4*)&e_lds[d * 68 + 4 * cg];
            acc[0][0] += zv.x * ev.x; acc[0][1] += zv.x * ev.y;
            acc[0][2] += zv.x * ev.z; acc[0][3] += zv.x * ev.w;
            acc[1][0] += zv.y * ev.x; acc[1][1] += zv.y * ev.y;
            acc[1][2] += zv.y * ev.z; acc[1][3] += zv.y * ev.w;
            acc[2][0] += zv.z * ev.x; acc[2][1] += zv.z * ev.y;
            acc[2][2] += zv.z * ev.z; acc[2][3] += zv.z * ev.w;
            acc[3][0] += zv.w * ev.x; acc[3][1] += zv.w * ev.y;
            acc[3][2] += zv.w * ev.z; acc[3][3] += zv.w * ev.w;
        }

#pragma unroll
        for (int i = 0; i < 4; ++i) {
#pragma unroll
            for (int j = 0; j < 4; ++j) {
                float dist = e2_lds[4 * cg + j] - 2.f * acc[i][j];
                int   kk   = k0 + 4 * cg + j;
                if (dist < best[i]) { best[i] = dist; bestk[i] = kk; }
            }
        }
    }

    // argmin reduce across the 16 cg lanes (same pg group); first-index tiebreak
#pragma unroll
    for (int i = 0; i < 4; ++i) {
        float bd = best[i];
        int   bk = bestk[i];
        for (int off = 8; off > 0; off >>= 1) {
            float od = __shfl_xor(bd, off, 16);
            int   ok = __shfl_xor(bk, off, 16);
            if (od < bd || (od == bd && ok < bk)) { bd = od; bk = ok; }
        }
        best[i] = bd; bestk[i] = bk;
    }

    __syncthreads();             // done reading e_lds; reuse as zq staging
    float* zq_lds = e_lds;

    float lsum = 0.f;
#pragma unroll
    for (int j = 0; j < 4; ++j) {
        int k = bestk[j];
        int p = 4 * pg + j;
        float4 ev = *(const float4*)(emb + (size_t)k * DIM + 4 * cg);
        float zv0 = z_lds[(4 * cg + 0) * 68 + p];
        float zv1 = z_lds[(4 * cg + 1) * 68 + p];
        float zv2 = z_lds[(4 * cg + 2) * 68 + p];
        float zv3 = z_lds[(4 * cg + 3) * 68 + p];
        zq_lds[(4 * cg + 0) * 68 + p] = ev.x;
        zq_lds[(4 * cg + 1) * 68 + p] = ev.y;
        zq_lds[(4 * cg + 2) * 68 + p] = ev.z;
        zq_lds[(4 * cg + 3) * 68 + p] = ev.w;
        float d0 = ev.x - zv0, d1 = ev.y - zv1, d2 = ev.z - zv2, d3 = ev.w - zv3;
        lsum += d0 * d0 + d1 * d1 + d2 * d2 + d3 * d3;
        atomicAdd(&bavg[(size_t)k * DIM + 4 * cg + 0], zv0);
        atomicAdd(&bavg[(size_t)k * DIM + 4 * cg + 1], zv1);
        atomicAdd(&bavg[(size_t)k * DIM + 4 * cg + 2], zv2);
        atomicAdd(&bavg[(size_t)k * DIM + 4 * cg + 3], zv3);
        if (cg == 0) {
            atomicAdd(&counts[k], 1.0f);
            idx_out[p0 + p] = (float)k;
        }
    }

    // block/wave loss reduction -> one atomic per wave
#pragma unroll
    for (int off = 32; off > 0; off >>= 1) lsum += __shfl_xor(lsum, off, 64);
    if ((t & 63) == 0) atomicAdd(loss_ws, lsum);

    __syncthreads();
    {   // coalesced z_q write-out: 4 float4 per thread, same pattern as z load
        int seg = t & 15, d0 = t >> 4;
#pragma unroll
        for (int r = 0; r < 4; ++r) {
            int d = d0 + 16 * r;
            float4 q = *(const float4*)&zq_lds[d * 68 + 4 * seg];
            *(float4*)(zq_out + (size_t)b * PLANE + d * HW + hw0 + 4 * seg) = q;
        }
    }
}

// -------------------- EMA finalize: outputs 4,5,6 --------------------
__global__ __launch_bounds__(256) void ema_kernel(
    const float* __restrict__ ema_cs, const float* __restrict__ ema_avg,
    const float* __restrict__ counts, const float* __restrict__ bavg,
    float* __restrict__ out_ncs, float* __restrict__ out_navg,
    float* __restrict__ out_nemb) {
    int tid = blockIdx.x * 256 + threadIdx.x;  // 0..131071 (K*D/4)
    int k = tid >> 4;
    float ncs = 0.99f * ema_cs[k] + 0.01f * counts[k];
    float den = ncs + 1e-5f;
    float4 ea = ((const float4*)ema_avg)[tid];
    float4 ba = ((const float4*)bavg)[tid];
    float4 na, ne;
    na.x = 0.99f * ea.x + 0.01f * ba.x;
    na.y = 0.99f * ea.y + 0.01f * ba.y;
    na.z = 0.99f * ea.z + 0.01f * ba.z;
    na.w = 0.99f * ea.w + 0.01f * ba.w;
    ne.x = na.x / den; ne.y = na.y / den; ne.z = na.z / den; ne.w = na.w / den;
    ((float4*)out_navg)[tid] = na;
    ((float4*)out_nemb)[tid] = ne;
    if ((tid & 15) == 0) out_ncs[k] = ncs;
}

// -------------------- scalars: loss + perplexity --------------------
__global__ __launch_bounds__(256) void scalars_kernel(
    const float* __restrict__ counts, const float* __restrict__ loss_ws,
    float* __restrict__ out_loss, float* __restrict__ out_perp) {
    __shared__ float red[4];
    float s = 0.f;
    for (int k = threadIdx.x; k < KCL; k += 256) {
        float p = counts[k] * (1.0f / (float)NPTS);
        s += p * logf(p + 1e-10f);
    }
#pragma unroll
    for (int off = 32; off > 0; off >>= 1) s += __shfl_xor(s, off, 64);
    if ((threadIdx.x & 63) == 0) red[threadIdx.x >> 6] = s;
    __syncthreads();
    if (threadIdx.x == 0) {
        float tot = red[0] + red[1] + red[2] + red[3];
        out_perp[0] = expf(-tot);
        out_loss[0] = 0.25f * loss_ws[0] / (float)(NPTS * DIM);
    }
}

extern "C" void kernel_launch(void* const* d_in, const int* in_sizes, int n_in,
                              void* d_out, int out_size, void* d_ws, size_t ws_size,
                              hipStream_t stream) {
    (void)in_sizes; (void)n_in; (void)out_size; (void)ws_size;
    const float* z       = (const float*)d_in[0];
    const float* emb     = (const float*)d_in[1];
    const float* ema_cs  = (const float*)d_in[2];
    const float* ema_avg = (const float*)d_in[3];

    float* out0      = (float*)d_out;            // z_quantized_st  [2097152]
    float* out_loss  = out0 + 2097152;           // loss            [1]
    float* out_perp  = out_loss + 1;             // perplexity      [1]
    float* out_idx   = out_perp + 1;             // encoding_indices[32768]
    float* out_nemb  = out_idx + NPTS;           // new_embedding   [524288]
    float* out_ncs   = out_nemb + KCL * DIM;     // new_cluster_size[8192]
    float* out_navg  = out_ncs + KCL;            // new_embedding_avg[524288]

    float* e2_ws     = (float*)d_ws;             // [8192]
    float* counts_ws = e2_ws + KCL;              // [8192]
    float* bavg_ws   = counts_ws + KCL;          // [524288]
    float* loss_ws   = bavg_ws + KCL * DIM;      // [1]

    // zero the accumulators (counts + bavg + loss scalar)
    hipMemsetAsync((void*)counts_ws, 0, (size_t)(KCL + KCL * DIM + 1) * sizeof(float), stream);

    e2_kernel<<<KCL / 256, 256, 0, stream>>>(emb, e2_ws);
    vq_main<<<NPTS / 64, 256, 0, stream>>>(z, emb, e2_ws, counts_ws, bavg_ws,
                                           loss_ws, out0, out_idx);
    ema_kernel<<<KCL * DIM / 4 / 256, 256, 0, stream>>>(ema_cs, ema_avg, counts_ws,
                                                        bavg_ws, out_ncs, out_navg, out_nemb);
    scalars_kernel<<<1, 256, 0, stream>>>(counts_ws, loss_ws, out_loss, out_perp);
}